// Round 6
// baseline (6176.020 us; speedup 1.0000x reference)
//
#include <hip/hip_runtime.h>

typedef unsigned short ushort_t;
typedef _Float16 h2 __attribute__((ext_vector_type(2)));
typedef _Float16 h8 __attribute__((ext_vector_type(8)));
typedef int i4 __attribute__((ext_vector_type(4)));
typedef float f4 __attribute__((ext_vector_type(4)));

#define T_TOT 2048
#define B_    64
#define H3_   768
#define QB    4            // batches per rec block
#define NBLK  16           // rec blocks (NBLK*QB == 64)

__device__ __forceinline__ float bf2f(ushort_t u){
  return __uint_as_float(((unsigned)u) << 16);
}
__device__ __forceinline__ ushort_t f2bf(float f){
  unsigned u = __float_as_uint(f);
  u += 0x7FFFu + ((u >> 16) & 1u);
  return (ushort_t)(u >> 16);
}
__device__ __forceinline__ h2 as_h2(int x){
  union { int i; h2 h; } u; u.i = x; return u.h;
}
#if __has_builtin(__builtin_amdgcn_fdot2)
__device__ __forceinline__ float fdot2_(h2 a, h2 b, float c){
  return __builtin_amdgcn_fdot2(a, b, c, false);
}
#else
__device__ __forceinline__ float fdot2_(h2 a, h2 b, float c){
  return c + (float)a[0]*(float)b[0] + (float)a[1]*(float)b[1];
}
#endif
__device__ __forceinline__ float sigm_(float x){ return 1.0f/(1.0f + __expf(-x)); }
__device__ __forceinline__ float tanh_(float x){ float e=__expf(2.0f*x); return 1.0f - 2.0f/(e+1.0f); }

__device__ __forceinline__ float qadd1(float x){
  int y = __builtin_amdgcn_mov_dpp(__float_as_int(x), 0xB1, 0xF, 0xF, true);
  return x + __int_as_float(y);
}
__device__ __forceinline__ float qadd2(float x){
  int y = __builtin_amdgcn_mov_dpp(__float_as_int(x), 0x4E, 0xF, 0xF, true);
  return x + __int_as_float(y);
}

// Barrier waiting only on LDS traffic (per-step ys global stores stay in flight).
__device__ __forceinline__ void barrier_lgkm(){
  asm volatile("s_waitcnt lgkmcnt(0)" ::: "memory");
  __builtin_amdgcn_s_barrier();
}

template<int F32>
__device__ __forceinline__ float ldf(const void* p, size_t i){
  if (F32) return ((const float*)p)[i];
  return bf2f(((const ushort_t*)p)[i]);
}

// ---------- phase-1 (unchanged) helpers ----------
template<int F32>
__device__ __forceinline__ void load_w_q(const void* __restrict__ W, int cc, int kk,
                                         h2* wr, h2* wz, h2* wn){
#pragma unroll
  for (int i = 0; i < 8; i++){
    int ch = (i + kk) & 7;
#pragma unroll
    for (int u = 0; u < 4; u++){
      int k0 = kk * 64 + ch * 8 + 2 * u;
      size_t r0 = (size_t)k0 * H3_;
      size_t r1 = r0 + H3_;
      int j = i * 4 + u;
      wr[j][0] = (_Float16)ldf<F32>(W, r0 + cc);
      wr[j][1] = (_Float16)ldf<F32>(W, r1 + cc);
      wz[j][0] = (_Float16)ldf<F32>(W, r0 + 256 + cc);
      wz[j][1] = (_Float16)ldf<F32>(W, r1 + 256 + cc);
      wn[j][0] = (_Float16)ldf<F32>(W, r0 + 512 + cc);
      wn[j][1] = (_Float16)ldf<F32>(W, r1 + 512 + cc);
    }
  }
}

__device__ __forceinline__ void dot_q(const _Float16* hrow, int kk,
                                      const h2* wr, const h2* wz, const h2* wn,
                                      float& ar, float& az, float& an){
#pragma unroll
  for (int i = 0; i < 8; i++){
    const i4* vp = (const i4*)(hrow + kk * 64 + (((i + kk) & 7) << 3));
    i4 v = *vp;
#pragma unroll
    for (int u = 0; u < 4; u++){
      h2 p = as_h2(v[u]);
      int j = i * 4 + u;
      ar = fdot2_(p, wr[j], ar);
      az = fdot2_(p, wz[j], az);
      an = fdot2_(p, wn[j], an);
    }
  }
}

// Dtype probe (unchanged).
__global__ void dtype_probe(const void* __restrict__ W, int* __restrict__ flag){
  const int lane = threadIdx.x;
  const ushort_t* p = (const ushort_t*)W;
  int s0, s1;
  { ushort_t h = p[4*lane];     int e = (h>>7)&0xFF; s0 = (e==0 || (e>=80 && e<=141)) ? 1:0; }
  { ushort_t h = p[4*lane + 2]; int e = (h>>7)&0xFF; s1 = (e==0 || (e>=80 && e<=141)) ? 1:0; }
  unsigned long long m0 = __ballot(s0);
  unsigned long long m1 = __ballot(s1);
  if (lane == 0){
    int sane = __popcll(m0) + __popcll(m1);
    *flag = (sane >= 96) ? 0 : 1;
  }
}

// Phase 1: xi = xs @ Wi (f16 out). Unchanged from round 4/5.
__global__ __launch_bounds__(1024, 1) void gru_xproj(
    const void* __restrict__ xs, const void* __restrict__ Wi,
    _Float16* __restrict__ xi, const int* __restrict__ flag, int t0, int Tc)
{
  const int lane = threadIdx.x;
  const int cc = lane >> 2, kk = lane & 3;
  const int f32 = *flag;

  h2 wr[32], wz[32], wn[32];
  if (f32) load_w_q<1>(Wi, cc, kk, wr, wz, wn);
  else     load_w_q<0>(Wi, cc, kk, wr, wz, wn);

  __shared__ __align__(16) _Float16 xb[4][256];
  _Float16* xf = &xb[0][0];
  const int groups = Tc * 16;
  for (int g = blockIdx.x; g < groups; g += gridDim.x){
    const size_t base = ((size_t)t0 * 64 + (size_t)g * 4) * 256;
    float v = f32 ? ((const float*)xs)[base + lane]
                  : bf2f(((const ushort_t*)xs)[base + lane]);
    xf[lane] = (_Float16)v;
    barrier_lgkm();
#pragma unroll
    for (int rr = 0; rr < 4; rr++){
      float ar = 0.f, az = 0.f, an = 0.f;
      dot_q(&xb[rr][0], kk, wr, wz, wn, ar, az, an);
      ar = qadd2(qadd1(ar));
      az = qadd2(qadd1(az));
      an = qadd2(qadd1(an));
      if (kk == 0){
        _Float16* o = xi + ((size_t)g * 4 + rr) * H3_;
        o[cc]       = (_Float16)ar;
        o[256 + cc] = (_Float16)az;
        o[512 + cc] = (_Float16)an;
      }
    }
    barrier_lgkm();
  }
}

// Phase 2, MFMA edition.
// 16 blocks x 4 batches. 16 waves/block; wave w owns output cols [48w,48w+48)
// (3 col-tiles of 16) with full K=256 (8 K-steps of 32).
// Wh lives in registers as B-fragments: 24 x h8 = 96 VGPR/lane.
// Per step: 8 LDS A-frag reads (lanes l&15<QB only) -> 24 MFMA -> gate LDS
// (stride-5 padded, conflict-free) -> barrier -> per-unit epilogue (1 unit/lane)
// -> h_tile writeback -> barrier.  MFMA k-slot mapping cancels (A and B use the
// same (g,e)->k bijection); relies only on m/n = lane&15 and the verified
// D layout row=4*(l>>4)+reg, col=l&15.
__global__ __launch_bounds__(1024, 1) void gru_rec_mfma(
    const _Float16* __restrict__ xi, const void* __restrict__ Wh,
    const void* __restrict__ bh, const void* __restrict__ bin,
    const void* __restrict__ c0, float* __restrict__ h_state,
    void* __restrict__ dout, const int* __restrict__ flag, int t0, int Tc)
{
  const int tid  = threadIdx.x;
  const int l    = tid & 63;
  const int w    = tid >> 6;          // wave 0..15
  const int l15  = l & 15;
  const int g    = l >> 4;            // k-group 0..3
  const int blk  = blockIdx.x;
  const int f32  = *flag;

  __shared__ __align__(16) _Float16 h_tile[QB][264];   // 528B rows: bank-clean A reads
  __shared__ __align__(16) float    gbuf[H3_ * 5];     // [col][5]: 4 rows + pad
  __shared__ __align__(16) float    bb[256][4];        // {br,bz,bn,bi} per col

  // ---- B-fragments: bfr[j][s][e] = Wh[32s+8g+e][48w+16j+l15] ----
  h8 bfr[3][8];
  if (f32){
#pragma unroll
    for (int j = 0; j < 3; j++)
#pragma unroll
      for (int s = 0; s < 8; s++)
#pragma unroll
        for (int e = 0; e < 8; e++)
          bfr[j][s][e] = (_Float16)ldf<1>(Wh, (size_t)(32*s + 8*g + e) * H3_ + 48*w + 16*j + l15);
  } else {
#pragma unroll
    for (int j = 0; j < 3; j++)
#pragma unroll
      for (int s = 0; s < 8; s++)
#pragma unroll
        for (int e = 0; e < 8; e++)
          bfr[j][s][e] = (_Float16)ldf<0>(Wh, (size_t)(32*s + 8*g + e) * H3_ + 48*w + 16*j + l15);
  }

  // ---- bias stash ----
  if (tid < 256){
    bb[tid][0] = f32 ? ldf<1>(bh, tid)        : ldf<0>(bh, tid);
    bb[tid][1] = f32 ? ldf<1>(bh, 256 + tid)  : ldf<0>(bh, 256 + tid);
    bb[tid][2] = f32 ? ldf<1>(bh, 512 + tid)  : ldf<0>(bh, 512 + tid);
    bb[tid][3] = f32 ? ldf<1>(bin, tid)       : ldf<0>(bin, tid);
  }

  // ---- unit ownership: lane -> (m, c); batch = QB*blk + m ----
  const int m     = tid >> 8;          // 0..3 (wave-uniform)
  const int c     = tid & 255;
  const int batch = QB * blk + m;

  float hcur;
  if (t0 == 0) hcur = f32 ? ldf<1>(c0, (size_t)batch*256 + c) : ldf<0>(c0, (size_t)batch*256 + c);
  else         hcur = h_state[batch*256 + c];
  h_tile[m][c] = (_Float16)hcur;

  ushort_t* outb = (ushort_t*)dout;  ushort_t* ysb = outb + 16384;
  float*    outf = (float*)dout;     float*    ysf = outf + 16384;

  barrier_lgkm();

  for (int t = 0; t < Tc; t++){
    // xi for THIS step: issue early; consumed after the barrier (covered by MFMA).
    const _Float16* xp = xi + ((size_t)t * 64 + batch) * H3_;
    float xr = (float)xp[c];
    float xz = (float)xp[256 + c];
    float xn = (float)xp[512 + c];

    // ---- MFMA: s-outer, j-inner; acc[j] static ----
    f4 acc0 = {0.f,0.f,0.f,0.f}, acc1 = {0.f,0.f,0.f,0.f}, acc2 = {0.f,0.f,0.f,0.f};
#pragma unroll
    for (int s = 0; s < 8; s++){
      h8 a = {};
      if (l15 < QB)
        a = *(const h8*)(&h_tile[l15][32*s + 8*g]);
      acc0 = __builtin_amdgcn_mfma_f32_16x16x32_f16(a, bfr[0][s], acc0, 0, 0, 0);
      acc1 = __builtin_amdgcn_mfma_f32_16x16x32_f16(a, bfr[1][s], acc1, 0, 0, 0);
      acc2 = __builtin_amdgcn_mfma_f32_16x16x32_f16(a, bfr[2][s], acc2, 0, 0, 0);
    }

    // ---- gate staging: D row r (batch r), col 48w+16j+l15; stride-5 padding ----
    if (g == 0){
      const int cb = 48*w + l15;
#pragma unroll
      for (int r = 0; r < 4; r++) gbuf[(cb     )*5 + r] = acc0[r];
#pragma unroll
      for (int r = 0; r < 4; r++) gbuf[(cb + 16)*5 + r] = acc1[r];
#pragma unroll
      for (int r = 0; r < 4; r++) gbuf[(cb + 32)*5 + r] = acc2[r];
    }
    barrier_lgkm();

    // ---- epilogue: one (m,c) unit per lane ----
    float gr = gbuf[(c      )*5 + m];
    float gz = gbuf[(c + 256)*5 + m];
    float gn = gbuf[(c + 512)*5 + m];
    f4 bv = *(const f4*)&bb[c][0];

    float r = sigm_(gr + bv[0] + xr);
    float z = sigm_(gz + bv[1] + xz);
    float n = tanh_(xn + bv[3] + r * (gn + bv[2]));
    float hnew = (1.0f - z) * n + z * hcur;
    hcur = hnew;

    h_tile[m][c] = (_Float16)hnew;
    size_t yi = ((size_t)(t0 + t) * 64 + batch) * 256 + c;
    if (f32) ysf[yi] = hnew; else ysb[yi] = f2bf(hnew);

    barrier_lgkm();
  }

  h_state[batch*256 + c] = hcur;
  if (t0 + Tc == T_TOT){
    if (f32) outf[batch*256 + c] = hcur;
    else     outb[batch*256 + c] = f2bf(hcur);
  }
}

extern "C" void kernel_launch(void* const* d_in, const int* in_sizes, int n_in,
                              void* d_out, int out_size, void* d_ws, size_t ws_size,
                              hipStream_t stream)
{
  const void* c0  = d_in[0];
  const void* xs  = d_in[1];
  const void* Wi  = d_in[2];
  const void* Wh  = d_in[3];
  const void* bh  = d_in[4];
  const void* bin = d_in[5];

  int*      flag    = (int*)d_ws;
  float*    h_state = (float*)((char*)d_ws + 512);
  _Float16* xi      = (_Float16*)((char*)d_ws + 512 + 65536);

  dtype_probe<<<dim3(1), dim3(64), 0, stream>>>(Wh, flag);

  const size_t base_off = 512 + 65536;
  const size_t per_t = (size_t)B_ * H3_ * sizeof(_Float16);   // 98304 B
  long avail_t = (ws_size > base_off + per_t)
                   ? (long)((ws_size - base_off) / per_t) : 1;
  if (avail_t < 1) avail_t = 1;
  if (avail_t > T_TOT) avail_t = T_TOT;
  int Tc = 1;
  while ((long)Tc * 2 <= avail_t) Tc <<= 1;                   // divides 2048

  for (int t0 = 0; t0 < T_TOT; t0 += Tc){
    gru_xproj<<<dim3(256), dim3(1024), 0, stream>>>(xs, Wi, xi, flag, t0, Tc);
    gru_rec_mfma<<<dim3(NBLK), dim3(1024), 0, stream>>>(xi, Wh, bh, bin, c0, h_state,
                                                        d_out, flag, t0, Tc);
  }
}